// Round 15
// baseline (347.092 us; speedup 1.0000x reference)
//
#include <hip/hip_runtime.h>
#include <cstdint>
#include <cstddef>

// Problem constants: B=64, C=3, H=W=64, F=96, K=8, h=w=32, C0=6, P=h*w=1024
// params channels: a[0:6) b[6:12) logpi[12:60) mu[60:108) s[108:156)

typedef unsigned short u16;
typedef __attribute__((ext_vector_type(8))) short short8;
typedef __attribute__((ext_vector_type(4))) float f32x4;
typedef __attribute__((ext_vector_type(16))) float f32x16;

__device__ __forceinline__ float sigm(float x){ return 1.0f/(1.0f+__expf(-x)); }

__device__ __forceinline__ u16 f2bf(float f){
    unsigned int u = __float_as_uint(f);
    u += 0x7fffu + ((u >> 16) & 1u);
    return (u16)(u >> 16);
}
__device__ __forceinline__ float bf2f(u16 v){
    unsigned int u = ((unsigned int)v) << 16;
    return __uint_as_float(u);
}

// ---------------- mega-prep: MFMA-conv1 + all weight repacks + LN transposes + initlog.
__global__ __launch_bounds__(256) void k_prep(
    const float* __restrict__ z, const float* __restrict__ c1w, const float* __restrict__ c1b,
    const float* __restrict__ gw, const float* __restrict__ c2w,
    const float* __restrict__ qkvw, const float* __restrict__ pw,
    const float* __restrict__ ln1g, const float* __restrict__ ln1b,
    const float* __restrict__ ln2g, const float* __restrict__ ln2b,
    const float* __restrict__ logdf,
    u16* __restrict__ x1b,
    u16* __restrict__ Wg, u16* __restrict__ W2,
    u16* __restrict__ Wqkv, u16* __restrict__ Wproj,
    float* __restrict__ gt1, float* __restrict__ bt1,
    float* __restrict__ gt2, float* __restrict__ bt2,
    float* __restrict__ outlog)
{
    int blk = blockIdx.x;
    int tid = threadIdx.x;
    __shared__ float tin[6][6][34];
    __shared__ __align__(16) u16 Wc[96][72];
    __shared__ __align__(16) u16 imc[128][72];

    if (blk < 512){
        int b  = blk >> 3;
        int pg = blk & 7;
        int r0 = pg*4;
        for (int e = tid; e < 96*72; e += 256){
            int oc = e/72, k = e%72;
            Wc[oc][k] = (k < 54) ? f2bf(c1w[oc*54 + k]) : (u16)0;
        }
        for (int idx = tid; idx < 6*6*34; idx += 256){
            int c = idx/204, rem = idx%204;
            int rr = rem/34, q = rem%34;
            int ii = r0 - 1 + rr, jj = q - 1;
            float v = 0.f;
            if ((unsigned)ii < 32u && (unsigned)jj < 32u){
                if (c < 3) v = z[((b*3+c)*64 + 2*ii)*64 + (2*jj+1)];        // p01
                else       v = z[((b*3+(c-3))*64 + (2*ii+1))*64 + 2*jj];    // p10
            }
            tin[c][rr][q] = v;
        }
        __syncthreads();
        for (int e = tid; e < 128*72; e += 256){
            int px = e/72, k = e%72;
            float v = 0.f;
            if (k < 54){
                int c = k/9, rr = (k%9)/3, dcc = k%3;
                v = tin[c][(px>>5)+rr][(px&31)+dcc];
            }
            imc[px][k] = f2bf(v);
        }
        __syncthreads();

        int w = tid >> 6, lane = tid & 63;
        int cc = lane & 15, gg = lane >> 4;
        f32x4 acc[2][6];
        #pragma unroll
        for (int u=0;u<2;++u)
            #pragma unroll
            for (int t=0;t<6;++t) acc[u][t] = (f32x4){0.f,0.f,0.f,0.f};

        #pragma unroll
        for (int ks=0; ks<2; ++ks){
            short8 a0 = *reinterpret_cast<const short8*>(&imc[w*32 + cc     ][ks*32 + 8*gg]);
            short8 a1 = *reinterpret_cast<const short8*>(&imc[w*32 + 16 + cc][ks*32 + 8*gg]);
            #pragma unroll
            for (int t=0; t<6; ++t){
                short8 bb = *reinterpret_cast<const short8*>(&Wc[t*16+cc][ks*32 + 8*gg]);
                acc[0][t] = __builtin_amdgcn_mfma_f32_16x16x32_bf16(a0, bb, acc[0][t], 0,0,0);
                acc[1][t] = __builtin_amdgcn_mfma_f32_16x16x32_bf16(a1, bb, acc[1][t], 0,0,0);
            }
        }

        #pragma unroll
        for (int u=0;u<2;++u){
            int p0 = pg*128 + w*32 + u*16 + gg*4;
            #pragma unroll
            for (int t=0;t<6;++t){
                int oc = t*16+cc;
                float bv = c1b[oc];
                #pragma unroll
                for (int r=0;r<4;++r)
                    x1b[((size_t)(b*1024) + p0 + r)*96 + oc] = f2bf(acc[u][t][r] + bv);
            }
        }
    } else if (blk < 1160){
        int idx = (blk-512)*256 + tid;                // < 9*192*96
        int tap = idx / (192*96);
        int rem = idx - tap*192*96;
        int ocp = rem / 96, ic = rem % 96;
        int obk = ocp/96, r = ocp%96, isB = r/48, i = r%48;
        int oc = obk*48 + i + isB*96;
        Wg[idx] = f2bf(gw[(size_t)(oc*96+ic)*9 + tap]);
    } else if (blk < 1700){
        int idx = (blk-1160)*256 + tid;               // < 9*160*96
        int tap = idx / (160*96);
        int rem = idx - tap*160*96;
        int oc = rem / 96, ic = rem % 96;
        W2[idx] = (oc < 156) ? f2bf(c2w[(size_t)(oc*96+ic)*9 + tap]) : (u16)0;
    } else if (blk < 1808){
        int idx = (blk-1700)*256 + tid;               // < 288*96
        Wqkv[idx] = f2bf(qkvw[idx]);
    } else if (blk < 1880){
        int idx = (blk-1808)*256 + tid;               // < 192*96
        int ocp = idx / 96, ic = idx % 96;
        int obk = ocp/96, r = ocp%96, isB = r/48, i = r%48;
        int oc = obk*48 + i + isB*96;
        Wproj[idx] = f2bf(pw[(size_t)oc*96 + ic]);
    } else if (blk < 2264){
        int idx = (blk-1880)*256 + tid;               // < 98304
        int c = idx >> 10, p = idx & 1023;
        gt1[p*96 + c] = ln1g[idx];
    } else if (blk < 2648){
        int idx = (blk-2264)*256 + tid;
        int c = idx >> 10, p = idx & 1023;
        bt1[p*96 + c] = ln1b[idx];
    } else if (blk < 3032){
        int idx = (blk-2648)*256 + tid;
        int c = idx >> 10, p = idx & 1023;
        gt2[p*96 + c] = ln2g[idx];
    } else if (blk < 3416){
        int idx = (blk-3032)*256 + tid;
        int c = idx >> 10, p = idx & 1023;
        bt2[p*96 + c] = ln2b[idx];
    } else {
        if (tid < 64) outlog[tid] = logdf[tid];
    }
}

// ---------------- gated conv: OC split across 2 blocks (paired), grid 1024 = 4/CU.
__global__ __launch_bounds__(256,4) void k_gconv(const u16* __restrict__ Xpb,
    const u16* __restrict__ Wt, const float* __restrict__ bias,
    u16* __restrict__ outb, float* __restrict__ partials)
{
    int blk  = blockIdx.x;
    int obk  = blk & 1;
    int pblk = (blk >> 1) & 7;
    int b    = blk >> 4;
    int tid  = threadIdx.x;
    int w = tid >> 6, lane = tid & 63;
    int cc = lane & 15, gg = lane >> 4;

    __shared__ __align__(16) u16 Ws[96][104];
    __shared__ float red[8];

    f32x4 acc[2][6];
    #pragma unroll
    for (int u=0;u<2;++u)
        #pragma unroll
        for (int t=0;t<6;++t) acc[u][t] = (f32x4){0.f,0.f,0.f,0.f};

    int base = pblk*128 + w*32;
    int ia = base >> 5;
    const u16* xb = Xpb + (size_t)b*1024*96;
    const u16* wbase = Wt + (size_t)obk*96*96;

    short8 wreg[5];
    #pragma unroll
    for (int i=0;i<5;++i){
        int c = tid + 256*i;
        if (c < 1152){
            int oc=c/12, ico=(c%12)*8;
            wreg[i] = *reinterpret_cast<const short8*>(wbase + oc*96 + ico);
        }
    }

    for (int tap=0; tap<9; ++tap){
        int dr = tap/3 - 1, dc = tap%3 - 1;
        __syncthreads();
        #pragma unroll
        for (int i=0;i<5;++i){
            int c = tid + 256*i;
            if (c < 1152){
                int oc=c/12, ico=(c%12)*8;
                *reinterpret_cast<short8*>(&Ws[oc][ico]) = wreg[i];
            }
        }
        if (tap < 8){
            const u16* wn = wbase + (size_t)(tap+1)*192*96;
            #pragma unroll
            for (int i=0;i<5;++i){
                int c = tid + 256*i;
                if (c < 1152){
                    int oc=c/12, ico=(c%12)*8;
                    wreg[i] = *reinterpret_cast<const short8*>(wn + oc*96 + ico);
                }
            }
        }
        __syncthreads();

        int ii = ia + dr;
        int jj0 = cc + dc, jj1 = cc + 16 + dc;
        bool rv = ((unsigned)ii < 32u);
        bool v0 = rv && ((unsigned)jj0 < 32u);
        bool v1 = rv && ((unsigned)jj1 < 32u);
        const u16* ar0 = xb + (ptrdiff_t)(ii*32 + jj0)*96 + 8*gg;
        const u16* ar1 = xb + (ptrdiff_t)(ii*32 + jj1)*96 + 8*gg;

        #pragma unroll
        for (int ks=0; ks<3; ++ks){
            short8 a0 = {0,0,0,0,0,0,0,0};
            short8 a1 = {0,0,0,0,0,0,0,0};
            if (v0) a0 = *reinterpret_cast<const short8*>(ar0 + ks*32);
            if (v1) a1 = *reinterpret_cast<const short8*>(ar1 + ks*32);
            #pragma unroll
            for (int t=0; t<6; ++t){
                short8 bb = *reinterpret_cast<const short8*>(&Ws[t*16+cc][ks*32+8*gg]);
                acc[0][t] = __builtin_amdgcn_mfma_f32_16x16x32_bf16(a0, bb, acc[0][t], 0,0,0);
                acc[1][t] = __builtin_amdgcn_mfma_f32_16x16x32_bf16(a1, bb, acc[1][t], 0,0,0);
            }
        }
    }

    float s = 0.f, ssq = 0.f;
    #pragma unroll
    for (int u=0;u<2;++u){
        int p0 = base + u*16 + gg*4;
        #pragma unroll
        for (int t=0;t<3;++t){
            int ocA = obk*48 + t*16+cc;
            float ba = bias[ocA], bbv = bias[ocA+96];
            #pragma unroll
            for (int r=0;r<4;++r){
                float res = bf2f(Xpb[((size_t)b*1024 + p0+r)*96 + ocA]);
                float va = acc[u][t][r]   + ba;
                float vb = acc[u][t+3][r] + bbv;
                float v = res + va*sigm(vb);
                outb[((size_t)b*1024 + p0+r)*96 + ocA] = f2bf(v);
                s += v; ssq += v*v;
            }
        }
    }
    #pragma unroll
    for (int o=32;o>0;o>>=1){ s += __shfl_down(s,o,64); ssq += __shfl_down(ssq,o,64); }
    if (lane==0){ red[w]=s; red[4+w]=ssq; }
    __syncthreads();
    if (tid==0){
        int slot = b*16 + pblk*2 + obk;
        partials[slot*2+0] = red[0]+red[1]+red[2]+red[3];
        partials[slot*2+1] = red[4]+red[5]+red[6]+red[7];
    }
}

// ---------------- LN apply with fused stats fold, flat coalesced elementwise.
__global__ __launch_bounds__(256) void k_lne(const u16* __restrict__ xb,
    const float* __restrict__ gt, const float* __restrict__ bt,
    const float* __restrict__ partials, u16* __restrict__ out)
{
    int b = blockIdx.x / 48, rem = blockIdx.x % 48;
    float s=0.f, ss=0.f;
    #pragma unroll
    for (int i=0;i<16;++i){ s += partials[(b*16+i)*2]; ss += partials[(b*16+i)*2+1]; }
    float mu = s/98304.f;
    float r = rsqrtf(ss/98304.f - mu*mu + 1e-5f);

    int e8 = rem*256 + threadIdx.x;
    size_t base = (size_t)b*98304 + (size_t)e8*8;
    short8 x8 = *reinterpret_cast<const short8*>(xb + base);
    const float* gp = gt + e8*8;
    const float* bp = bt + e8*8;
    short8 o8;
    #pragma unroll
    for (int i=0;i<8;++i)
        o8[i] = (short)f2bf((bf2f((u16)x8[i]) - mu)*r*gp[i] + bp[i]);
    *reinterpret_cast<short8*>(out + base) = o8;
}

// ---------------- conv2 (bf16 output): OC 160 split across 2 blocks of 80.
__global__ __launch_bounds__(256,4) void k_conv2m(const u16* __restrict__ Xpb,
    const u16* __restrict__ Wt, const float* __restrict__ bias,
    u16* __restrict__ out)
{
    int blk  = blockIdx.x;
    int obk  = blk & 1;
    int pblk = (blk >> 1) & 7;
    int b    = blk >> 4;
    int tid  = threadIdx.x;
    int w = tid >> 6, lane = tid & 63;
    int cc = lane & 15, gg = lane >> 4;

    __shared__ __align__(16) u16 Ws[80][104];

    f32x4 acc[2][5];
    #pragma unroll
    for (int u=0;u<2;++u)
        #pragma unroll
        for (int t=0;t<5;++t) acc[u][t] = (f32x4){0.f,0.f,0.f,0.f};

    int base = pblk*128 + w*32;
    int ia = base >> 5;
    const u16* xb = Xpb + (size_t)b*1024*96;
    const u16* wbase = Wt + (size_t)obk*80*96;

    short8 wreg[4];
    #pragma unroll
    for (int i=0;i<4;++i){
        int c = tid + 256*i;
        if (c < 960){
            int oc=c/12, ico=(c%12)*8;
            wreg[i] = *reinterpret_cast<const short8*>(wbase + oc*96 + ico);
        }
    }

    for (int tap=0; tap<9; ++tap){
        int dr = tap/3 - 1, dc = tap%3 - 1;
        __syncthreads();
        #pragma unroll
        for (int i=0;i<4;++i){
            int c = tid + 256*i;
            if (c < 960){
                int oc=c/12, ico=(c%12)*8;
                *reinterpret_cast<short8*>(&Ws[oc][ico]) = wreg[i];
            }
        }
        if (tap < 8){
            const u16* wn = wbase + (size_t)(tap+1)*160*96;
            #pragma unroll
            for (int i=0;i<4;++i){
                int c = tid + 256*i;
                if (c < 960){
                    int oc=c/12, ico=(c%12)*8;
                    wreg[i] = *reinterpret_cast<const short8*>(wn + oc*96 + ico);
                }
            }
        }
        __syncthreads();

        int ii = ia + dr;
        int jj0 = cc + dc, jj1 = cc + 16 + dc;
        bool rv = ((unsigned)ii < 32u);
        bool v0 = rv && ((unsigned)jj0 < 32u);
        bool v1 = rv && ((unsigned)jj1 < 32u);
        const u16* ar0 = xb + (ptrdiff_t)(ii*32 + jj0)*96 + 8*gg;
        const u16* ar1 = xb + (ptrdiff_t)(ii*32 + jj1)*96 + 8*gg;

        #pragma unroll
        for (int ks=0; ks<3; ++ks){
            short8 a0 = {0,0,0,0,0,0,0,0};
            short8 a1 = {0,0,0,0,0,0,0,0};
            if (v0) a0 = *reinterpret_cast<const short8*>(ar0 + ks*32);
            if (v1) a1 = *reinterpret_cast<const short8*>(ar1 + ks*32);
            #pragma unroll
            for (int t=0; t<5; ++t){
                short8 bb = *reinterpret_cast<const short8*>(&Ws[t*16+cc][ks*32+8*gg]);
                acc[0][t] = __builtin_amdgcn_mfma_f32_16x16x32_bf16(a0, bb, acc[0][t], 0,0,0);
                acc[1][t] = __builtin_amdgcn_mfma_f32_16x16x32_bf16(a1, bb, acc[1][t], 0,0,0);
            }
        }
    }

    #pragma unroll
    for (int u=0;u<2;++u){
        int p0 = base + u*16 + gg*4;
        #pragma unroll
        for (int t=0;t<5;++t){
            int oc = obk*80 + t*16+cc;
            if (oc < 156){
                float bv = bias[oc];
                u16* op = out + ((size_t)b*156 + oc)*1024 + p0;
                #pragma unroll
                for (int r=0;r<4;++r) op[r] = f2bf(acc[u][t][r] + bv);
            }
        }
    }
}

// ---------------- qkv: OC 288 split across 2 blocks of 144, grid 1024 = 4/CU.
// Q prescaled bf16 pixel-major; K,V in 32x32-MFMA fragment-slot order.
__global__ __launch_bounds__(256,4) void k_qkvm(const u16* __restrict__ Xpb,
    const u16* __restrict__ Wt, const float* __restrict__ bias,
    u16* __restrict__ Qb, u16* __restrict__ Kf, u16* __restrict__ Vf)
{
    int blk  = blockIdx.x;
    int obk  = blk & 1;
    int pblk = (blk >> 1) & 7;
    int b    = blk >> 4;
    int tid  = threadIdx.x;
    int w = tid >> 6, lane = tid & 63;
    int cc = lane & 15, gg = lane >> 4;
    const float scale = 0.10206207262f;   // 1/sqrt(96)

    __shared__ __align__(16) u16 Ws[144][104];
    {
        const u16* wp = Wt + (size_t)obk*144*96;
        for (int c = tid; c < 144*12; c += 256){
            int oc = c/12, ico = (c%12)*8;
            *reinterpret_cast<short8*>(&Ws[oc][ico]) =
                *reinterpret_cast<const short8*>(wp + oc*96 + ico);
        }
    }

    f32x4 acc[2][9];
    #pragma unroll
    for (int u=0;u<2;++u)
        #pragma unroll
        for (int t=0;t<9;++t) acc[u][t] = (f32x4){0.f,0.f,0.f,0.f};

    int base = pblk*128 + w*32;
    const u16* xb = Xpb + ((size_t)b*1024 + base)*96;
    __syncthreads();

    #pragma unroll
    for (int ks=0; ks<3; ++ks){
        short8 a0 = *reinterpret_cast<const short8*>(xb + (size_t)cc*96      + ks*32 + 8*gg);
        short8 a1 = *reinterpret_cast<const short8*>(xb + (size_t)(cc+16)*96 + ks*32 + 8*gg);
        #pragma unroll
        for (int t=0; t<9; ++t){
            short8 bb = *reinterpret_cast<const short8*>(&Ws[t*16+cc][ks*32+8*gg]);
            acc[0][t] = __builtin_amdgcn_mfma_f32_16x16x32_bf16(a0, bb, acc[0][t], 0,0,0);
            acc[1][t] = __builtin_amdgcn_mfma_f32_16x16x32_bf16(a1, bb, acc[1][t], 0,0,0);
        }
    }

    #pragma unroll
    for (int u=0;u<2;++u){
        int p0 = base + u*16 + gg*4;
        #pragma unroll
        for (int t=0;t<9;++t){
            int n = obk*144 + t*16+cc;
            float bv = bias[n];
            #pragma unroll
            for (int r=0;r<4;++r){
                int p = p0 + r;
                float av = acc[u][t][r] + bv;
                if (n < 96){
                    Qb[((size_t)(b*1024+p))*96 + n] = f2bf(av*scale);
                } else if (n < 192){
                    int f = n-96;
                    int jt = p>>6, kl = p&63;
                    int tt = kl>>5;
                    int lanep = (kl&31) + 32*((f>>3)&1);
                    int ks = f>>4, j = f&7;
                    Kf[(size_t)(b*16+jt)*6144 + (size_t)(((tt*6+ks)*64 + lanep))*8 + j] = f2bf(av);
                } else {
                    int f = n-192;
                    int jt = p>>6, kl = p&63;
                    int ks2 = kl>>4, hi = (kl>>3)&1, j = kl&7;
                    int ft2 = f>>5;
                    int lanep = (f&31) + 32*hi;
                    Vf[(size_t)(b*16+jt)*6144 + (size_t)(((ft2*4+ks2)*64 + lanep))*8 + j] = f2bf(av);
                }
            }
        }
    }
}

// ---------------- flash attention v6: 32x32x16 MFMA, key-split across 2 waves (raw-exp makes
// the combine additive: O=(O0+O1)/(l0+l1)). B-frags loaded DIRECTLY from global fragment-order
// K/V (L2-resident, coalesced 1KB/wave) — no K/V LDS, ZERO in-loop barriers. P in pad-engineered
// conflict-free per-wave LDS. Block = 128 thr = 32 queries x 2 splits; grid = 2048, XCD-swizzled.
__global__ __launch_bounds__(128,3) void k_attn(const u16* __restrict__ Qb,
    const u16* __restrict__ Kf, const u16* __restrict__ Vf, u16* __restrict__ Ob)
{
    int qt = blockIdx.x >> 6;       // 0..31 (32-query tile)
    int b  = blockIdx.x & 63;
    int tid = threadIdx.x;          // 0..127
    int w  = tid >> 6;              // key-split index 0..1
    int lane = tid & 63;
    int ln32 = lane & 31;
    int hl = lane >> 5;

    __shared__ __align__(16) u16 Ps[2][2112];     // per-wave padded P: ks2*528 + hi*264 + q*8 + j
    __shared__ float Cmb[64][65];                 // split-combine buffer (padded, conflict-free)

    int q0 = qt*32;

    // Q A-frags (32x32): m=ln32, k=hl*8+j; feat = ks*16 + hl*8 + j (prescaled)
    short8 qf[6];
    {
        const u16* qrow = Qb + ((size_t)(b*1024 + q0 + ln32))*96 + hl*8;
        #pragma unroll
        for (int ks=0; ks<6; ++ks)
            qf[ks] = *reinterpret_cast<const short8*>(qrow + ks*16);
    }

    f32x16 Oacc[3];
    #pragma unroll
    for (int ft=0; ft<3; ++ft)
        #pragma unroll
        for (int r=0; r<16; ++r) Oacc[ft][r] = 0.f;
    float l_acc[16];
    #pragma unroll
    for (int r=0; r<16; ++r) l_acc[r] = 0.f;

    const u16* Kb0 = Kf + (size_t)(b*16)*6144;
    const u16* Vb0 = Vf + (size_t)(b*16)*6144;

    for (int jt = w*8; jt < w*8 + 8; ++jt){
        const u16* kt = Kb0 + (size_t)jt*6144;
        const u16* vt = Vb0 + (size_t)jt*6144;

        // S = Q K^T : 2 key-subtiles of 32, K-dim 96 over 6 ks-steps of 16
        f32x16 Sacc[2];
        #pragma unroll
        for (int t=0;t<2;++t)
            #pragma unroll
            for (int r=0;r<16;++r) Sacc[t][r] = 0.f;
        #pragma unroll
        for (int ks=0; ks<6; ++ks){
            #pragma unroll
            for (int t=0; t<2; ++t){
                short8 bb = *reinterpret_cast<const short8*>(kt + ((t*6+ks)*64 + lane)*8);
                Sacc[t] = __builtin_amdgcn_mfma_f32_32x32x16_bf16(qf[ks], bb, Sacc[t], 0,0,0);
            }
        }

        // raw exp + deferred row-sum; P -> padded per-wave LDS in 32x32 A-frag order
        #pragma unroll
        for (int t=0; t<2; ++t){
            int off0 = (t*2 + (ln32>>4))*528 + ((ln32>>3)&1)*264 + (lane&7);
            #pragma unroll
            for (int r=0; r<16; ++r){
                int q = 4*hl + (r&3) + 8*(r>>2);
                float p = __expf(Sacc[t][r]);
                l_acc[r] += p;
                Ps[w][off0 + q*8] = f2bf(p);
            }
        }

        // O += P V : K-dim 64 keys over 4 ks2-steps of 16; 3 f-tiles of 32 (B direct from global)
        #pragma unroll
        for (int ks2=0; ks2<4; ++ks2){
            short8 pa = *reinterpret_cast<const short8*>(&Ps[w][ks2*528 + hl*264 + ln32*8]);
            #pragma unroll
            for (int ft=0; ft<3; ++ft){
                short8 vb = *reinterpret_cast<const short8*>(vt + ((ft*4+ks2)*64 + lane)*8);
                Oacc[ft] = __builtin_amdgcn_mfma_f32_32x32x16_bf16(pa, vb, Oacc[ft], 0,0,0);
            }
        }
    }

    // in-wave row-sum over the 32 columns (each 32-lane half independent)
    #pragma unroll
    for (int r=0; r<16; ++r){
        #pragma unroll
        for (int msk=1; msk<32; msk<<=1)
            l_acc[r] += __shfl_xor(l_acc[r], msk, 64);
    }

    // split combine: wave 1 deposits unnormalized O + l; wave 0 adds, normalizes, writes
    if (w == 1){
        #pragma unroll
        for (int ft=0; ft<3; ++ft)
            #pragma unroll
            for (int r=0; r<16; ++r) Cmb[lane][ft*16+r] = Oacc[ft][r];
        #pragma unroll
        for (int r=0; r<16; ++r) Cmb[lane][48+r] = l_acc[r];
    }
    __syncthreads();
    if (w == 0){
        #pragma unroll
        for (int r=0; r<16; ++r){
            float lt = l_acc[r] + Cmb[lane][48+r];
            float linv = 1.0f / lt;
            int q = 4*hl + (r&3) + 8*(r>>2);
            #pragma unroll
            for (int ft=0; ft<3; ++ft){
                float o = Oacc[ft][r] + Cmb[lane][ft*16+r];
                Ob[((size_t)(b*1024 + q0 + q))*96 + ft*32 + ln32] = f2bf(o*linv);
            }
        }
    }
}

// ---------------- proj: OC split across 2 blocks (paired), grid 1024 = 4/CU.
__global__ __launch_bounds__(256,4) void k_projm(const u16* __restrict__ Opb,
    const u16* __restrict__ Wt, const float* __restrict__ bias,
    const u16* __restrict__ xlnb, u16* __restrict__ outb, float* __restrict__ partials)
{
    int blk  = blockIdx.x;
    int obk  = blk & 1;
    int pblk = (blk >> 1) & 7;
    int b    = blk >> 4;
    int tid  = threadIdx.x;
    int w = tid >> 6, lane = tid & 63;
    int cc = lane & 15, gg = lane >> 4;

    __shared__ __align__(16) u16 Ws[96][104];
    __shared__ float red[8];
    {
        const u16* wp = Wt + (size_t)obk*96*96;
        for (int c = tid; c < 96*12; c += 256){
            int oc = c/12, ico = (c%12)*8;
            *reinterpret_cast<short8*>(&Ws[oc][ico]) =
                *reinterpret_cast<const short8*>(wp + oc*96 + ico);
        }
    }

    f32x4 acc[2][6];
    #pragma unroll
    for (int u=0;u<2;++u)
        #pragma unroll
        for (int t=0;t<6;++t) acc[u][t] = (f32x4){0.f,0.f,0.f,0.f};

    int base = pblk*128 + w*32;
    const u16* xb = Opb + ((size_t)b*1024 + base)*96;
    __syncthreads();

    #pragma unroll
    for (int ks=0; ks<3; ++ks){
        short8 a0 = *reinterpret_cast<const short8*>(xb + (size_t)cc*96      + ks*32 + 8*gg);
        short8 a1 = *reinterpret_cast<const short8*>(xb + (size_t)(cc+16)*96 + ks*32 + 8*gg);
        #pragma unroll
        for (int t=0; t<6; ++t){
            short8 bb = *reinterpret_cast<const short8*>(&Ws[t*16+cc][ks*32+8*gg]);
            acc[0][t] = __builtin_amdgcn_mfma_f32_16x16x32_bf16(a0, bb, acc[0][t], 0,0,0);
            acc[1][t] = __builtin_amdgcn_mfma_f32_16x16x32_bf16(a1, bb, acc[1][t], 0,0,0);
        }
    }

    const u16* resb = xlnb + (size_t)b*1024*96;
    float s = 0.f, ssq = 0.f;
    #pragma unroll
    for (int u=0;u<2;++u){
        int p0 = base + u*16 + gg*4;
        #pragma unroll
        for (int t=0;t<3;++t){
            int ocA = obk*48 + t*16+cc;
            float ba = bias[ocA], bbv = bias[ocA+96];
            #pragma unroll
            for (int r=0;r<4;++r){
                float ga = acc[u][t][r]   + ba;
                float gb = acc[u][t+3][r] + bbv;
                float res = bf2f(resb[(size_t)(p0+r)*96 + ocA]);
                float v = res + ga * sigm(gb);
                outb[((size_t)b*1024 + p0+r)*96 + ocA] = f2bf(v);
                s += v; ssq += v*v;
            }
        }
    }
    #pragma unroll
    for (int o=32;o>0;o>>=1){ s += __shfl_down(s,o,64); ssq += __shfl_down(ssq,o,64); }
    if (lane==0){ red[w]=s; red[4+w]=ssq; }
    __syncthreads();
    if (tid==0){
        int slot = b*16 + pblk*2 + obk;
        partials[slot*2+0] = red[0]+red[1]+red[2]+red[3];
        partials[slot*2+1] = red[4]+red[5]+red[6]+red[7];
    }
}

// ---------------- mixture transform + merge + log-det (params bf16 ch-major)
__global__ __launch_bounds__(256) void k_mix(const float* __restrict__ z,
    const u16* __restrict__ params, const float* __restrict__ a_ls_p,
    const float* __restrict__ a_b_p, float* __restrict__ out_z, float* __restrict__ out_log)
{
    int b = blockIdx.x / 24;
    int rem = blockIdx.x % 24;
    int c0 = rem / 4;
    int pix = (rem & 3)*256 + threadIdx.x;
    int i = pix >> 5, j = pix & 31;
    float als = a_ls_p[0], abv = a_b_p[0];
    const u16* pb = params + (size_t)b*156*1024;
    float logacc = 0.f;

    if (c0 < 3){
        int idx01 = ((b*3+c0)*64 + 2*i)*64 + 2*j+1;
        int idx10 = ((b*3+c0)*64 + 2*i+1)*64 + 2*j;
        out_z[idx01] = z[idx01];
        out_z[idx10] = z[idx10];
    }

    {
        float z0v = (c0<3) ? z[((b*3+c0)*64 + 2*i)*64 + 2*j]
                           : z[((b*3+(c0-3))*64 + 2*i+1)*64 + 2*j+1];
        float a_raw = bf2f(pb[(c0)*1024 + pix]);
        float bco   = bf2f(pb[(6+c0)*1024 + pix]);
        float lp[8], mu[8], sv[8];
        float m1 = -1e30f;
        #pragma unroll
        for (int k=0;k<8;++k){
            lp[k] = bf2f(pb[(12 + k*6 + c0)*1024 + pix]);
            mu[k] = bf2f(pb[(60 + k*6 + c0)*1024 + pix]);
            sv[k] = bf2f(pb[(108 + k*6 + c0)*1024 + pix]);
            m1 = fmaxf(m1, lp[k]);
        }
        float se = 0.f;
        #pragma unroll
        for (int k=0;k<8;++k) se += __expf(lp[k]-m1);
        float lse = m1 + __logf(se);
        float xm = 0.f, mt = -1e30f;
        float t[8];
        #pragma unroll
        for (int k=0;k<8;++k){
            float lpn = lp[k] - lse;
            float u = (z0v - mu[k]) * __expf(-sv[k]);
            float au = fabsf(u);
            xm += __expf(lpn) * (1.f/(1.f+__expf(-u)));
            float lss = -(au + 2.f*log1pf(__expf(-au)));
            float tk = lpn - sv[k] + lss;
            t[k] = tk; mt = fmaxf(mt, tk);
        }
        float se2 = 0.f;
        #pragma unroll
        for (int k=0;k<8;++k) se2 += __expf(t[k]-mt);
        logacc += mt + __logf(se2);
        xm = fminf(fmaxf(xm, 1e-6f), 1.f-1e-6f);
        float lx = __logf(xm), l1x = log1pf(-xm);
        logacc += -lx - l1x;
        float aa = tanhf(a_raw)*als + abv;
        float z0n = (lx - l1x)*__expf(aa) + bco;
        logacc += aa;
        int oidx = (c0<3) ? ((b*3+c0)*64 + 2*i)*64 + 2*j
                          : ((b*3+(c0-3))*64 + 2*i+1)*64 + 2*j+1;
        out_z[oidx] = z0n;
    }

    #pragma unroll
    for (int o=32;o>0;o>>=1) logacc += __shfl_down(logacc, o, 64);
    __shared__ float part[4];
    if ((threadIdx.x&63)==0) part[threadIdx.x>>6] = logacc;
    __syncthreads();
    if (threadIdx.x==0){
        atomicAdd(out_log + b, part[0]+part[1]+part[2]+part[3]);
    }
}

extern "C" void kernel_launch(void* const* d_in, const int* in_sizes, int n_in,
                              void* d_out, int out_size, void* d_ws, size_t ws_size,
                              hipStream_t stream)
{
    const float* z     = (const float*)d_in[0];
    const float* logdf = (const float*)d_in[1];
    const float* c1w   = (const float*)d_in[2];
    const float* c1b   = (const float*)d_in[3];
    const float* gw    = (const float*)d_in[4];
    const float* gcb   = (const float*)d_in[5];
    const float* ln1g  = (const float*)d_in[6];
    const float* ln1b  = (const float*)d_in[7];
    const float* qkvw  = (const float*)d_in[8];
    const float* qkvb  = (const float*)d_in[9];
    const float* pw    = (const float*)d_in[10];
    const float* pbb   = (const float*)d_in[11];
    const float* ln2g  = (const float*)d_in[12];
    const float* ln2b  = (const float*)d_in[13];
    const float* c2w   = (const float*)d_in[14];
    const float* c2b   = (const float*)d_in[15];
    const float* als   = (const float*)d_in[16];
    const float* ab    = (const float*)d_in[17];

    float* out_z   = (float*)d_out;
    float* out_log = out_z + 786432;

    // workspace (float units)
    float* ws     = (float*)d_ws;
    u16*   x1b    = (u16*)(ws + 0);            // A: conv1 out bf16 (B,1024,96)
    u16*   xg_b   = (u16*)(ws + 3145728);      // B: gated-gconv out bf16
    u16*   xlnb   = (u16*)(ws + 6291456);      // C: LN1 out bf16 (live thru projm)
    u16*   Vf     = (u16*)(ws + 9437184);      // D: V fragment-order bf16
    u16*   Ob     = (u16*)(ws + 12582912);     // E: attn out bf16
    u16*   x2b    = (u16*)(ws + 15728640);     // F: projm out bf16
    u16*   Qb     = x1b;                       // A reuse (x1b dead after gconv)
    u16*   Kf     = xg_b;                      // B reuse (xg_b dead after lne1)
    u16*   xln2b  = xlnb;                      // C reuse (xlnb dead after projm)
    u16*   params = (u16*)(ws + 9437184);      // bf16 (B,156,1024) over D/E (dead by conv2)
    const size_t T = 19660800;
    float* gt1    = ws + T;
    float* bt1    = ws + T + 98304;
    float* gt2    = ws + T + 196608;
    float* bt2    = ws + T + 294912;
    float* part1  = ws + T + 393216;           // 2048
    float* part2  = ws + T + 395264;           // 2048
    u16*   Wg     = (u16*)(ws + T + 397568);   // [9][192][96] packed-paired
    u16*   W2     = (u16*)(ws + T + 480512);   // [9][160][96]
    u16*   Wqkv   = (u16*)(ws + T + 549632);   // [288][96]
    u16*   Wproj  = (u16*)(ws + T + 563456);   // [192][96] packed-paired

    k_prep   <<<3417, 256, 0, stream>>>(z, c1w, c1b, gw, c2w, qkvw, pw,
                                        ln1g, ln1b, ln2g, ln2b, logdf,
                                        x1b, Wg, W2, Wqkv, Wproj,
                                        gt1, bt1, gt2, bt2, out_log);
    k_gconv  <<<1024, 256, 0, stream>>>(x1b, Wg, gcb, xg_b, part1);
    k_lne    <<<3072, 256, 0, stream>>>(xg_b, gt1, bt1, part1, xlnb);
    k_qkvm   <<<1024, 256, 0, stream>>>(xlnb, Wqkv, qkvb, Qb, Kf, Vf);
    k_attn   <<<2048, 128, 0, stream>>>(Qb, Kf, Vf, Ob);
    k_projm  <<<1024, 256, 0, stream>>>(Ob, Wproj, pbb, xlnb, x2b, part2);
    k_lne    <<<3072, 256, 0, stream>>>(x2b, gt2, bt2, part2, xln2b);
    k_conv2m <<<1024, 256, 0, stream>>>(xln2b, W2, c2b, params);
    k_mix    <<<1536, 256, 0, stream>>>(z, params, als, ab, out_z, out_log);
}

// Round 16
// 280.143 us; speedup vs baseline: 1.2390x; 1.2390x over previous
//
#include <hip/hip_runtime.h>
#include <cstdint>
#include <cstddef>

// Problem constants: B=64, C=3, H=W=64, F=96, K=8, h=w=32, C0=6, P=h*w=1024
// params channels: a[0:6) b[6:12) logpi[12:60) mu[60:108) s[108:156)

typedef unsigned short u16;
typedef __attribute__((ext_vector_type(8))) short short8;
typedef __attribute__((ext_vector_type(4))) float f32x4;

__device__ __forceinline__ float sigm(float x){ return 1.0f/(1.0f+__expf(-x)); }

__device__ __forceinline__ u16 f2bf(float f){
    unsigned int u = __float_as_uint(f);
    u += 0x7fffu + ((u >> 16) & 1u);
    return (u16)(u >> 16);
}
__device__ __forceinline__ float bf2f(u16 v){
    unsigned int u = ((unsigned int)v) << 16;
    return __uint_as_float(u);
}

// ---------------- mega-prep: MFMA-conv1 + all weight repacks + LN transposes + initlog.
// block ranges: [0,512) conv1; [512,1160) gconv-paired; [1160,1700) conv2; [1700,1808) qkv;
// [1808,1880) proj-paired; [1880,2264) gt1; [2264,2648) bt1; [2648,3032) gt2; [3032,3416) bt2;
// 3416 initlog.  Total 3417 blocks.
__global__ __launch_bounds__(256) void k_prep(
    const float* __restrict__ z, const float* __restrict__ c1w, const float* __restrict__ c1b,
    const float* __restrict__ gw, const float* __restrict__ c2w,
    const float* __restrict__ qkvw, const float* __restrict__ pw,
    const float* __restrict__ ln1g, const float* __restrict__ ln1b,
    const float* __restrict__ ln2g, const float* __restrict__ ln2b,
    const float* __restrict__ logdf,
    u16* __restrict__ x1b,
    u16* __restrict__ Wg, u16* __restrict__ W2,
    u16* __restrict__ Wqkv, u16* __restrict__ Wproj,
    float* __restrict__ gt1, float* __restrict__ bt1,
    float* __restrict__ gt2, float* __restrict__ bt2,
    float* __restrict__ outlog)
{
    int blk = blockIdx.x;
    int tid = threadIdx.x;
    __shared__ float tin[6][6][34];             // conv1 halo tile
    __shared__ __align__(16) u16 Wc[96][72];    // conv1 weights bf16, K padded 54->72
    __shared__ __align__(16) u16 imc[128][72];  // im2col bf16

    if (blk < 512){
        // ---- conv1 as MFMA im2col GEMM: 128 px x 96 oc, K=54 padded to 64
        int b  = blk >> 3;
        int pg = blk & 7;
        int r0 = pg*4;
        for (int e = tid; e < 96*72; e += 256){
            int oc = e/72, k = e%72;
            Wc[oc][k] = (k < 54) ? f2bf(c1w[oc*54 + k]) : (u16)0;
        }
        for (int idx = tid; idx < 6*6*34; idx += 256){
            int c = idx/204, rem = idx%204;
            int rr = rem/34, q = rem%34;
            int ii = r0 - 1 + rr, jj = q - 1;
            float v = 0.f;
            if ((unsigned)ii < 32u && (unsigned)jj < 32u){
                if (c < 3) v = z[((b*3+c)*64 + 2*ii)*64 + (2*jj+1)];        // p01
                else       v = z[((b*3+(c-3))*64 + (2*ii+1))*64 + 2*jj];    // p10
            }
            tin[c][rr][q] = v;
        }
        __syncthreads();
        for (int e = tid; e < 128*72; e += 256){
            int px = e/72, k = e%72;
            float v = 0.f;
            if (k < 54){
                int c = k/9, rr = (k%9)/3, dcc = k%3;
                v = tin[c][(px>>5)+rr][(px&31)+dcc];
            }
            imc[px][k] = f2bf(v);
        }
        __syncthreads();

        int w = tid >> 6, lane = tid & 63;
        int cc = lane & 15, gg = lane >> 4;
        f32x4 acc[2][6];
        #pragma unroll
        for (int u=0;u<2;++u)
            #pragma unroll
            for (int t=0;t<6;++t) acc[u][t] = (f32x4){0.f,0.f,0.f,0.f};

        #pragma unroll
        for (int ks=0; ks<2; ++ks){
            short8 a0 = *reinterpret_cast<const short8*>(&imc[w*32 + cc     ][ks*32 + 8*gg]);
            short8 a1 = *reinterpret_cast<const short8*>(&imc[w*32 + 16 + cc][ks*32 + 8*gg]);
            #pragma unroll
            for (int t=0; t<6; ++t){
                short8 bb = *reinterpret_cast<const short8*>(&Wc[t*16+cc][ks*32 + 8*gg]);
                acc[0][t] = __builtin_amdgcn_mfma_f32_16x16x32_bf16(a0, bb, acc[0][t], 0,0,0);
                acc[1][t] = __builtin_amdgcn_mfma_f32_16x16x32_bf16(a1, bb, acc[1][t], 0,0,0);
            }
        }

        #pragma unroll
        for (int u=0;u<2;++u){
            int p0 = pg*128 + w*32 + u*16 + gg*4;
            #pragma unroll
            for (int t=0;t<6;++t){
                int oc = t*16+cc;
                float bv = c1b[oc];
                #pragma unroll
                for (int r=0;r<4;++r)
                    x1b[((size_t)(b*1024) + p0 + r)*96 + oc] = f2bf(acc[u][t][r] + bv);
            }
        }
    } else if (blk < 1160){
        int idx = (blk-512)*256 + tid;                // < 9*192*96
        int tap = idx / (192*96);
        int rem = idx - tap*192*96;
        int ocp = rem / 96, ic = rem % 96;
        int obk = ocp/96, r = ocp%96, isB = r/48, i = r%48;
        int oc = obk*48 + i + isB*96;
        Wg[idx] = f2bf(gw[(size_t)(oc*96+ic)*9 + tap]);
    } else if (blk < 1700){
        int idx = (blk-1160)*256 + tid;               // < 9*160*96
        int tap = idx / (160*96);
        int rem = idx - tap*160*96;
        int oc = rem / 96, ic = rem % 96;
        W2[idx] = (oc < 156) ? f2bf(c2w[(size_t)(oc*96+ic)*9 + tap]) : (u16)0;
    } else if (blk < 1808){
        int idx = (blk-1700)*256 + tid;               // < 288*96
        Wqkv[idx] = f2bf(qkvw[idx]);
    } else if (blk < 1880){
        int idx = (blk-1808)*256 + tid;               // < 192*96
        int ocp = idx / 96, ic = idx % 96;
        int obk = ocp/96, r = ocp%96, isB = r/48, i = r%48;
        int oc = obk*48 + i + isB*96;
        Wproj[idx] = f2bf(pw[(size_t)oc*96 + ic]);
    } else if (blk < 2264){
        int idx = (blk-1880)*256 + tid;               // < 98304
        int c = idx >> 10, p = idx & 1023;
        gt1[p*96 + c] = ln1g[idx];
    } else if (blk < 2648){
        int idx = (blk-2264)*256 + tid;
        int c = idx >> 10, p = idx & 1023;
        bt1[p*96 + c] = ln1b[idx];
    } else if (blk < 3032){
        int idx = (blk-2648)*256 + tid;
        int c = idx >> 10, p = idx & 1023;
        gt2[p*96 + c] = ln2g[idx];
    } else if (blk < 3416){
        int idx = (blk-3032)*256 + tid;
        int c = idx >> 10, p = idx & 1023;
        bt2[p*96 + c] = ln2b[idx];
    } else {
        if (tid < 64) outlog[tid] = logdf[tid];
    }
}

// ---------------- gated conv: OC split across 2 blocks (paired), grid 1024 = 4/CU.
__global__ __launch_bounds__(256,4) void k_gconv(const u16* __restrict__ Xpb,
    const u16* __restrict__ Wt, const float* __restrict__ bias,
    u16* __restrict__ outb, float* __restrict__ partials)
{
    int blk  = blockIdx.x;
    int obk  = blk & 1;
    int pblk = (blk >> 1) & 7;
    int b    = blk >> 4;
    int tid  = threadIdx.x;
    int w = tid >> 6, lane = tid & 63;
    int cc = lane & 15, gg = lane >> 4;

    __shared__ __align__(16) u16 Ws[96][104];
    __shared__ float red[8];

    f32x4 acc[2][6];
    #pragma unroll
    for (int u=0;u<2;++u)
        #pragma unroll
        for (int t=0;t<6;++t) acc[u][t] = (f32x4){0.f,0.f,0.f,0.f};

    int base = pblk*128 + w*32;
    int ia = base >> 5;
    const u16* xb = Xpb + (size_t)b*1024*96;
    const u16* wbase = Wt + (size_t)obk*96*96;

    short8 wreg[5];
    #pragma unroll
    for (int i=0;i<5;++i){
        int c = tid + 256*i;
        if (c < 1152){
            int oc=c/12, ico=(c%12)*8;
            wreg[i] = *reinterpret_cast<const short8*>(wbase + oc*96 + ico);
        }
    }

    for (int tap=0; tap<9; ++tap){
        int dr = tap/3 - 1, dc = tap%3 - 1;
        __syncthreads();
        #pragma unroll
        for (int i=0;i<5;++i){
            int c = tid + 256*i;
            if (c < 1152){
                int oc=c/12, ico=(c%12)*8;
                *reinterpret_cast<short8*>(&Ws[oc][ico]) = wreg[i];
            }
        }
        if (tap < 8){
            const u16* wn = wbase + (size_t)(tap+1)*192*96;
            #pragma unroll
            for (int i=0;i<5;++i){
                int c = tid + 256*i;
                if (c < 1152){
                    int oc=c/12, ico=(c%12)*8;
                    wreg[i] = *reinterpret_cast<const short8*>(wn + oc*96 + ico);
                }
            }
        }
        __syncthreads();

        int ii = ia + dr;
        int jj0 = cc + dc, jj1 = cc + 16 + dc;
        bool rv = ((unsigned)ii < 32u);
        bool v0 = rv && ((unsigned)jj0 < 32u);
        bool v1 = rv && ((unsigned)jj1 < 32u);
        const u16* ar0 = xb + (ptrdiff_t)(ii*32 + jj0)*96 + 8*gg;
        const u16* ar1 = xb + (ptrdiff_t)(ii*32 + jj1)*96 + 8*gg;

        #pragma unroll
        for (int ks=0; ks<3; ++ks){
            short8 a0 = {0,0,0,0,0,0,0,0};
            short8 a1 = {0,0,0,0,0,0,0,0};
            if (v0) a0 = *reinterpret_cast<const short8*>(ar0 + ks*32);
            if (v1) a1 = *reinterpret_cast<const short8*>(ar1 + ks*32);
            #pragma unroll
            for (int t=0; t<6; ++t){
                short8 bb = *reinterpret_cast<const short8*>(&Ws[t*16+cc][ks*32+8*gg]);
                acc[0][t] = __builtin_amdgcn_mfma_f32_16x16x32_bf16(a0, bb, acc[0][t], 0,0,0);
                acc[1][t] = __builtin_amdgcn_mfma_f32_16x16x32_bf16(a1, bb, acc[1][t], 0,0,0);
            }
        }
    }

    float s = 0.f, ssq = 0.f;
    #pragma unroll
    for (int u=0;u<2;++u){
        int p0 = base + u*16 + gg*4;
        #pragma unroll
        for (int t=0;t<3;++t){
            int ocA = obk*48 + t*16+cc;
            float ba = bias[ocA], bbv = bias[ocA+96];
            #pragma unroll
            for (int r=0;r<4;++r){
                float res = bf2f(Xpb[((size_t)b*1024 + p0+r)*96 + ocA]);
                float va = acc[u][t][r]   + ba;
                float vb = acc[u][t+3][r] + bbv;
                float v = res + va*sigm(vb);
                outb[((size_t)b*1024 + p0+r)*96 + ocA] = f2bf(v);
                s += v; ssq += v*v;
            }
        }
    }
    #pragma unroll
    for (int o=32;o>0;o>>=1){ s += __shfl_down(s,o,64); ssq += __shfl_down(ssq,o,64); }
    if (lane==0){ red[w]=s; red[4+w]=ssq; }
    __syncthreads();
    if (tid==0){
        int slot = b*16 + pblk*2 + obk;
        partials[slot*2+0] = red[0]+red[1]+red[2]+red[3];
        partials[slot*2+1] = red[4]+red[5]+red[6]+red[7];
    }
}

// ---------------- LN apply with fused stats fold, flat coalesced elementwise.
__global__ __launch_bounds__(256) void k_lne(const u16* __restrict__ xb,
    const float* __restrict__ gt, const float* __restrict__ bt,
    const float* __restrict__ partials, u16* __restrict__ out)
{
    int b = blockIdx.x / 48, rem = blockIdx.x % 48;
    float s=0.f, ss=0.f;
    #pragma unroll
    for (int i=0;i<16;++i){ s += partials[(b*16+i)*2]; ss += partials[(b*16+i)*2+1]; }
    float mu = s/98304.f;
    float r = rsqrtf(ss/98304.f - mu*mu + 1e-5f);

    int e8 = rem*256 + threadIdx.x;
    size_t base = (size_t)b*98304 + (size_t)e8*8;
    short8 x8 = *reinterpret_cast<const short8*>(xb + base);
    const float* gp = gt + e8*8;
    const float* bp = bt + e8*8;
    short8 o8;
    #pragma unroll
    for (int i=0;i<8;++i)
        o8[i] = (short)f2bf((bf2f((u16)x8[i]) - mu)*r*gp[i] + bp[i]);
    *reinterpret_cast<short8*>(out + base) = o8;
}

// ---------------- conv2 (bf16 output): OC 160 split across 2 blocks of 80.
__global__ __launch_bounds__(256,4) void k_conv2m(const u16* __restrict__ Xpb,
    const u16* __restrict__ Wt, const float* __restrict__ bias,
    u16* __restrict__ out)
{
    int blk  = blockIdx.x;
    int obk  = blk & 1;
    int pblk = (blk >> 1) & 7;
    int b    = blk >> 4;
    int tid  = threadIdx.x;
    int w = tid >> 6, lane = tid & 63;
    int cc = lane & 15, gg = lane >> 4;

    __shared__ __align__(16) u16 Ws[80][104];

    f32x4 acc[2][5];
    #pragma unroll
    for (int u=0;u<2;++u)
        #pragma unroll
        for (int t=0;t<5;++t) acc[u][t] = (f32x4){0.f,0.f,0.f,0.f};

    int base = pblk*128 + w*32;
    int ia = base >> 5;
    const u16* xb = Xpb + (size_t)b*1024*96;
    const u16* wbase = Wt + (size_t)obk*80*96;

    short8 wreg[4];
    #pragma unroll
    for (int i=0;i<4;++i){
        int c = tid + 256*i;
        if (c < 960){
            int oc=c/12, ico=(c%12)*8;
            wreg[i] = *reinterpret_cast<const short8*>(wbase + oc*96 + ico);
        }
    }

    for (int tap=0; tap<9; ++tap){
        int dr = tap/3 - 1, dc = tap%3 - 1;
        __syncthreads();
        #pragma unroll
        for (int i=0;i<4;++i){
            int c = tid + 256*i;
            if (c < 960){
                int oc=c/12, ico=(c%12)*8;
                *reinterpret_cast<short8*>(&Ws[oc][ico]) = wreg[i];
            }
        }
        if (tap < 8){
            const u16* wn = wbase + (size_t)(tap+1)*160*96;
            #pragma unroll
            for (int i=0;i<4;++i){
                int c = tid + 256*i;
                if (c < 960){
                    int oc=c/12, ico=(c%12)*8;
                    wreg[i] = *reinterpret_cast<const short8*>(wn + oc*96 + ico);
                }
            }
        }
        __syncthreads();

        int ii = ia + dr;
        int jj0 = cc + dc, jj1 = cc + 16 + dc;
        bool rv = ((unsigned)ii < 32u);
        bool v0 = rv && ((unsigned)jj0 < 32u);
        bool v1 = rv && ((unsigned)jj1 < 32u);
        const u16* ar0 = xb + (ptrdiff_t)(ii*32 + jj0)*96 + 8*gg;
        const u16* ar1 = xb + (ptrdiff_t)(ii*32 + jj1)*96 + 8*gg;

        #pragma unroll
        for (int ks=0; ks<3; ++ks){
            short8 a0 = {0,0,0,0,0,0,0,0};
            short8 a1 = {0,0,0,0,0,0,0,0};
            if (v0) a0 = *reinterpret_cast<const short8*>(ar0 + ks*32);
            if (v1) a1 = *reinterpret_cast<const short8*>(ar1 + ks*32);
            #pragma unroll
            for (int t=0; t<5; ++t){
                short8 bb = *reinterpret_cast<const short8*>(&Ws[t*16+cc][ks*32+8*gg]);
                acc[0][t] = __builtin_amdgcn_mfma_f32_16x16x32_bf16(a0, bb, acc[0][t], 0,0,0);
                acc[1][t] = __builtin_amdgcn_mfma_f32_16x16x32_bf16(a1, bb, acc[1][t], 0,0,0);
            }
        }
    }

    #pragma unroll
    for (int u=0;u<2;++u){
        int p0 = base + u*16 + gg*4;
        #pragma unroll
        for (int t=0;t<5;++t){
            int oc = obk*80 + t*16+cc;
            if (oc < 156){
                float bv = bias[oc];
                u16* op = out + ((size_t)b*156 + oc)*1024 + p0;
                #pragma unroll
                for (int r=0;r<4;++r) op[r] = f2bf(acc[u][t][r] + bv);
            }
        }
    }
}

// ---------------- qkv: OC 288 split across 2 blocks of 144, grid 1024 = 4/CU.
// Q prescaled bf16 pixel-major; K,V in 16x16-MFMA fragment-slot order.
__global__ __launch_bounds__(256,4) void k_qkvm(const u16* __restrict__ Xpb,
    const u16* __restrict__ Wt, const float* __restrict__ bias,
    u16* __restrict__ Qb, u16* __restrict__ Kf, u16* __restrict__ Vf)
{
    int blk  = blockIdx.x;
    int obk  = blk & 1;
    int pblk = (blk >> 1) & 7;
    int b    = blk >> 4;
    int tid  = threadIdx.x;
    int w = tid >> 6, lane = tid & 63;
    int cc = lane & 15, gg = lane >> 4;
    const float scale = 0.10206207262f;   // 1/sqrt(96)

    __shared__ __align__(16) u16 Ws[144][104];
    {
        const u16* wp = Wt + (size_t)obk*144*96;
        for (int c = tid; c < 144*12; c += 256){
            int oc = c/12, ico = (c%12)*8;
            *reinterpret_cast<short8*>(&Ws[oc][ico]) =
                *reinterpret_cast<const short8*>(wp + oc*96 + ico);
        }
    }

    f32x4 acc[2][9];
    #pragma unroll
    for (int u=0;u<2;++u)
        #pragma unroll
        for (int t=0;t<9;++t) acc[u][t] = (f32x4){0.f,0.f,0.f,0.f};

    int base = pblk*128 + w*32;
    const u16* xb = Xpb + ((size_t)b*1024 + base)*96;
    __syncthreads();

    #pragma unroll
    for (int ks=0; ks<3; ++ks){
        short8 a0 = *reinterpret_cast<const short8*>(xb + (size_t)cc*96      + ks*32 + 8*gg);
        short8 a1 = *reinterpret_cast<const short8*>(xb + (size_t)(cc+16)*96 + ks*32 + 8*gg);
        #pragma unroll
        for (int t=0; t<9; ++t){
            short8 bb = *reinterpret_cast<const short8*>(&Ws[t*16+cc][ks*32+8*gg]);
            acc[0][t] = __builtin_amdgcn_mfma_f32_16x16x32_bf16(a0, bb, acc[0][t], 0,0,0);
            acc[1][t] = __builtin_amdgcn_mfma_f32_16x16x32_bf16(a1, bb, acc[1][t], 0,0,0);
        }
    }

    #pragma unroll
    for (int u=0;u<2;++u){
        int p0 = base + u*16 + gg*4;
        #pragma unroll
        for (int t=0;t<9;++t){
            int n = obk*144 + t*16+cc;
            float bv = bias[n];
            #pragma unroll
            for (int r=0;r<4;++r){
                int p = p0 + r;
                float av = acc[u][t][r] + bv;
                if (n < 96){
                    Qb[((size_t)(b*1024+p))*96 + n] = f2bf(av*scale);
                } else if (n < 192){
                    int f = n-96;
                    int jt = p>>6, t16 = (p>>4)&3, ccs = p&15;
                    int ks = f>>5, ggs = (f>>3)&3, j = f&7;
                    Kf[(size_t)(b*16+jt)*6144 + (size_t)(((t16*3+ks)*4+ggs)*16+ccs)*8 + j] = f2bf(av);
                } else {
                    int f = n-192;
                    int jt = p>>6, kl = p&63;
                    int kk = kl>>5, ggs = (kl>>3)&3, j = kl&7;
                    int ft = f>>4, ccs = f&15;
                    Vf[(size_t)(b*16+jt)*6144 + (size_t)(((ft*2+kk)*4+ggs)*16+ccs)*8 + j] = f2bf(av);
                }
            }
        }
    }
}

// ---------------- flash attention (round-13 structure): raw-exp softmax, fragment-order K/V,
// conflict-free LDS, register prefetch, XCD-swizzled grid, 4 blocks/CU.
__global__ __launch_bounds__(256,4) void k_attn(const u16* __restrict__ Qb,
    const u16* __restrict__ Kf, const u16* __restrict__ Vf, u16* __restrict__ Ob)
{
    int qt = blockIdx.x >> 6;       // 0..15
    int b  = blockIdx.x & 63;
    int tid = threadIdx.x;
    int w  = tid >> 6;
    int lane = tid & 63;
    int cc = lane & 15;
    int gg = lane >> 4;

    __shared__ __align__(16) u16 Ks[6144];
    __shared__ __align__(16) u16 Vs[6144];
    __shared__ __align__(16) u16 Ps[4][2048];

    int q0 = qt*64 + w*16;

    short8 qf[3];
    {
        const u16* qrow = Qb + ((size_t)(b*1024 + q0 + cc))*96;
        #pragma unroll
        for (int ks=0; ks<3; ++ks)
            qf[ks] = *reinterpret_cast<const short8*>(qrow + ks*32 + 8*gg);
    }

    f32x4 Oacc[6];
    #pragma unroll
    for (int ft=0; ft<6; ++ft) Oacc[ft] = (f32x4){0.f,0.f,0.f,0.f};
    float l_r[4] = {0.f,0.f,0.f,0.f};

    const u16* Kb0 = Kf + (size_t)(b*16)*6144;
    const u16* Vb0 = Vf + (size_t)(b*16)*6144;

    short8 kreg[3], vreg[3];
    #pragma unroll
    for (int i=0;i<3;++i){
        int s8 = (tid + 256*i)*8;
        kreg[i] = *reinterpret_cast<const short8*>(Kb0 + s8);
        vreg[i] = *reinterpret_cast<const short8*>(Vb0 + s8);
    }

    for (int jt=0; jt<16; ++jt){
        __syncthreads();
        #pragma unroll
        for (int i=0;i<3;++i){
            int s8 = (tid + 256*i)*8;
            *reinterpret_cast<short8*>(Ks + s8) = kreg[i];
            *reinterpret_cast<short8*>(Vs + s8) = vreg[i];
        }
        if (jt < 15){
            const u16* kn = Kb0 + (size_t)(jt+1)*6144;
            const u16* vn = Vb0 + (size_t)(jt+1)*6144;
            #pragma unroll
            for (int i=0;i<3;++i){
                int s8 = (tid + 256*i)*8;
                kreg[i] = *reinterpret_cast<const short8*>(kn + s8);
                vreg[i] = *reinterpret_cast<const short8*>(vn + s8);
            }
        }
        __syncthreads();

        f32x4 Sacc[4];
        #pragma unroll
        for (int t=0;t<4;++t) Sacc[t] = (f32x4){0.f,0.f,0.f,0.f};
        #pragma unroll
        for (int ks=0; ks<3; ++ks){
            #pragma unroll
            for (int t=0; t<4; ++t){
                short8 bb = *reinterpret_cast<const short8*>(Ks + ((t*3+ks)*64 + lane)*8);
                Sacc[t] = __builtin_amdgcn_mfma_f32_16x16x32_bf16(qf[ks], bb, Sacc[t], 0,0,0);
            }
        }

        #pragma unroll
        for (int t=0; t<4; ++t){
            int kk = t>>1;
            int ggs = ((t&1)<<1) | (cc>>3);
            int jj = cc&7;
            #pragma unroll
            for (int r=0; r<4; ++r){
                float p = __expf(Sacc[t][r]);
                l_r[r] += p;
                Ps[w][((kk*4 + ggs)*16 + (4*gg+r))*8 + jj] = f2bf(p);
            }
        }

        #pragma unroll
        for (int kk=0; kk<2; ++kk){
            short8 pa = *reinterpret_cast<const short8*>(&Ps[w][(kk*64 + lane)*8]);
            #pragma unroll
            for (int ft=0; ft<6; ++ft){
                short8 vb = *reinterpret_cast<const short8*>(Vs + ((ft*2+kk)*64 + lane)*8);
                Oacc[ft] = __builtin_amdgcn_mfma_f32_16x16x32_bf16(pa, vb, Oacc[ft], 0,0,0);
            }
        }
    }

    #pragma unroll
    for (int r=0; r<4; ++r){
        #pragma unroll
        for (int msk=1; msk<16; msk<<=1) l_r[r] += __shfl_xor(l_r[r], msk, 64);
    }
    float linv[4];
    #pragma unroll
    for (int r=0; r<4; ++r) linv[r] = 1.0f / l_r[r];
    #pragma unroll
    for (int ft=0; ft<6; ++ft)
        #pragma unroll
        for (int r=0; r<4; ++r)
            Ob[((size_t)(b*1024 + q0 + 4*gg + r))*96 + ft*16 + cc]
                = f2bf(Oacc[ft][r]*linv[r]);
}

// ---------------- proj: OC split across 2 blocks (paired), grid 1024 = 4/CU.
__global__ __launch_bounds__(256,4) void k_projm(const u16* __restrict__ Opb,
    const u16* __restrict__ Wt, const float* __restrict__ bias,
    const u16* __restrict__ xlnb, u16* __restrict__ outb, float* __restrict__ partials)
{
    int blk  = blockIdx.x;
    int obk  = blk & 1;
    int pblk = (blk >> 1) & 7;
    int b    = blk >> 4;
    int tid  = threadIdx.x;
    int w = tid >> 6, lane = tid & 63;
    int cc = lane & 15, gg = lane >> 4;

    __shared__ __align__(16) u16 Ws[96][104];
    __shared__ float red[8];
    {
        const u16* wp = Wt + (size_t)obk*96*96;
        for (int c = tid; c < 96*12; c += 256){
            int oc = c/12, ico = (c%12)*8;
            *reinterpret_cast<short8*>(&Ws[oc][ico]) =
                *reinterpret_cast<const short8*>(wp + oc*96 + ico);
        }
    }

    f32x4 acc[2][6];
    #pragma unroll
    for (int u=0;u<2;++u)
        #pragma unroll
        for (int t=0;t<6;++t) acc[u][t] = (f32x4){0.f,0.f,0.f,0.f};

    int base = pblk*128 + w*32;
    const u16* xb = Opb + ((size_t)b*1024 + base)*96;
    __syncthreads();

    #pragma unroll
    for (int ks=0; ks<3; ++ks){
        short8 a0 = *reinterpret_cast<const short8*>(xb + (size_t)cc*96      + ks*32 + 8*gg);
        short8 a1 = *reinterpret_cast<const short8*>(xb + (size_t)(cc+16)*96 + ks*32 + 8*gg);
        #pragma unroll
        for (int t=0; t<6; ++t){
            short8 bb = *reinterpret_cast<const short8*>(&Ws[t*16+cc][ks*32+8*gg]);
            acc[0][t] = __builtin_amdgcn_mfma_f32_16x16x32_bf16(a0, bb, acc[0][t], 0,0,0);
            acc[1][t] = __builtin_amdgcn_mfma_f32_16x16x32_bf16(a1, bb, acc[1][t], 0,0,0);
        }
    }

    const u16* resb = xlnb + (size_t)b*1024*96;
    float s = 0.f, ssq = 0.f;
    #pragma unroll
    for (int u=0;u<2;++u){
        int p0 = base + u*16 + gg*4;
        #pragma unroll
        for (int t=0;t<3;++t){
            int ocA = obk*48 + t*16+cc;
            float ba = bias[ocA], bbv = bias[ocA+96];
            #pragma unroll
            for (int r=0;r<4;++r){
                float ga = acc[u][t][r]   + ba;
                float gb = acc[u][t+3][r] + bbv;
                float res = bf2f(resb[(size_t)(p0+r)*96 + ocA]);
                float v = res + ga * sigm(gb);
                outb[((size_t)b*1024 + p0+r)*96 + ocA] = f2bf(v);
                s += v; ssq += v*v;
            }
        }
    }
    #pragma unroll
    for (int o=32;o>0;o>>=1){ s += __shfl_down(s,o,64); ssq += __shfl_down(ssq,o,64); }
    if (lane==0){ red[w]=s; red[4+w]=ssq; }
    __syncthreads();
    if (tid==0){
        int slot = b*16 + pblk*2 + obk;
        partials[slot*2+0] = red[0]+red[1]+red[2]+red[3];
        partials[slot*2+1] = red[4]+red[5]+red[6]+red[7];
    }
}

// ---------------- mixture transform + merge + log-det (params bf16 ch-major)
__global__ __launch_bounds__(256) void k_mix(const float* __restrict__ z,
    const u16* __restrict__ params, const float* __restrict__ a_ls_p,
    const float* __restrict__ a_b_p, float* __restrict__ out_z, float* __restrict__ out_log)
{
    int b = blockIdx.x / 24;
    int rem = blockIdx.x % 24;
    int c0 = rem / 4;
    int pix = (rem & 3)*256 + threadIdx.x;
    int i = pix >> 5, j = pix & 31;
    float als = a_ls_p[0], abv = a_b_p[0];
    const u16* pb = params + (size_t)b*156*1024;
    float logacc = 0.f;

    if (c0 < 3){
        int idx01 = ((b*3+c0)*64 + 2*i)*64 + 2*j+1;
        int idx10 = ((b*3+c0)*64 + 2*i+1)*64 + 2*j;
        out_z[idx01] = z[idx01];
        out_z[idx10] = z[idx10];
    }

    {
        float z0v = (c0<3) ? z[((b*3+c0)*64 + 2*i)*64 + 2*j]
                           : z[((b*3+(c0-3))*64 + 2*i+1)*64 + 2*j+1];
        float a_raw = bf2f(pb[(c0)*1024 + pix]);
        float bco   = bf2f(pb[(6+c0)*1024 + pix]);
        float lp[8], mu[8], sv[8];
        float m1 = -1e30f;
        #pragma unroll
        for (int k=0;k<8;++k){
            lp[k] = bf2f(pb[(12 + k*6 + c0)*1024 + pix]);
            mu[k] = bf2f(pb[(60 + k*6 + c0)*1024 + pix]);
            sv[k] = bf2f(pb[(108 + k*6 + c0)*1024 + pix]);
            m1 = fmaxf(m1, lp[k]);
        }
        float se = 0.f;
        #pragma unroll
        for (int k=0;k<8;++k) se += __expf(lp[k]-m1);
        float lse = m1 + __logf(se);
        float xm = 0.f, mt = -1e30f;
        float t[8];
        #pragma unroll
        for (int k=0;k<8;++k){
            float lpn = lp[k] - lse;
            float u = (z0v - mu[k]) * __expf(-sv[k]);
            float au = fabsf(u);
            xm += __expf(lpn) * (1.f/(1.f+__expf(-u)));
            float lss = -(au + 2.f*log1pf(__expf(-au)));
            float tk = lpn - sv[k] + lss;
            t[k] = tk; mt = fmaxf(mt, tk);
        }
        float se2 = 0.f;
        #pragma unroll
        for (int k=0;k<8;++k) se2 += __expf(t[k]-mt);
        logacc += mt + __logf(se2);
        xm = fminf(fmaxf(xm, 1e-6f), 1.f-1e-6f);
        float lx = __logf(xm), l1x = log1pf(-xm);
        logacc += -lx - l1x;
        float aa = tanhf(a_raw)*als + abv;
        float z0n = (lx - l1x)*__expf(aa) + bco;
        logacc += aa;
        int oidx = (c0<3) ? ((b*3+c0)*64 + 2*i)*64 + 2*j
                          : ((b*3+(c0-3))*64 + 2*i+1)*64 + 2*j+1;
        out_z[oidx] = z0n;
    }

    #pragma unroll
    for (int o=32;o>0;o>>=1) logacc += __shfl_down(logacc, o, 64);
    __shared__ float part[4];
    if ((threadIdx.x&63)==0) part[threadIdx.x>>6] = logacc;
    __syncthreads();
    if (threadIdx.x==0){
        atomicAdd(out_log + b, part[0]+part[1]+part[2]+part[3]);
    }
}

extern "C" void kernel_launch(void* const* d_in, const int* in_sizes, int n_in,
                              void* d_out, int out_size, void* d_ws, size_t ws_size,
                              hipStream_t stream)
{
    const float* z     = (const float*)d_in[0];
    const float* logdf = (const float*)d_in[1];
    const float* c1w   = (const float*)d_in[2];
    const float* c1b   = (const float*)d_in[3];
    const float* gw    = (const float*)d_in[4];
    const float* gcb   = (const float*)d_in[5];
    const float* ln1g  = (const float*)d_in[6];
    const float* ln1b  = (const float*)d_in[7];
    const float* qkvw  = (const float*)d_in[8];
    const float* qkvb  = (const float*)d_in[9];
    const float* pw    = (const float*)d_in[10];
    const float* pbb   = (const float*)d_in[11];
    const float* ln2g  = (const float*)d_in[12];
    const float* ln2b  = (const float*)d_in[13];
    const float* c2w   = (const float*)d_in[14];
    const float* c2b   = (const float*)d_in[15];
    const float* als   = (const float*)d_in[16];
    const float* ab    = (const float*)d_in[17];

    float* out_z   = (float*)d_out;
    float* out_log = out_z + 786432;

    // workspace (float units)
    float* ws     = (float*)d_ws;
    u16*   x1b    = (u16*)(ws + 0);            // A: conv1 out bf16 (B,1024,96)
    u16*   xg_b   = (u16*)(ws + 3145728);      // B: gated-gconv out bf16
    u16*   xlnb   = (u16*)(ws + 6291456);      // C: LN1 out bf16 (live thru projm)
    u16*   Vf     = (u16*)(ws + 9437184);      // D: V fragment-order bf16
    u16*   Ob     = (u16*)(ws + 12582912);     // E: attn out bf16
    u16*   x2b    = (u16*)(ws + 15728640);     // F: projm out bf16
    u16*   Qb     = x1b;                       // A reuse (x1b dead after gconv)
    u16*   Kf     = xg_b;                      // B reuse (xg_b dead after lne1)
    u16*   xln2b  = xlnb;                      // C reuse (xlnb dead after projm)
    u16*   params = (u16*)(ws + 9437184);      // bf16 (B,156,1024) over D/E (dead by conv2)
    const size_t T = 19660800;
    float* gt1    = ws + T;
    float* bt1    = ws + T + 98304;
    float* gt2    = ws + T + 196608;
    float* bt2    = ws + T + 294912;
    float* part1  = ws + T + 393216;           // 2048
    float* part2  = ws + T + 395264;           // 2048
    u16*   Wg     = (u16*)(ws + T + 397568);   // [9][192][96] packed-paired
    u16*   W2     = (u16*)(ws + T + 480512);   // [9][160][96]
    u16*   Wqkv   = (u16*)(ws + T + 549632);   // [288][96]
    u16*   Wproj  = (u16*)(ws + T + 563456);   // [192][96] packed-paired

    k_prep   <<<3417, 256, 0, stream>>>(z, c1w, c1b, gw, c2w, qkvw, pw,
                                        ln1g, ln1b, ln2g, ln2b, logdf,
                                        x1b, Wg, W2, Wqkv, Wproj,
                                        gt1, bt1, gt2, bt2, out_log);
    k_gconv  <<<1024, 256, 0, stream>>>(x1b, Wg, gcb, xg_b, part1);
    k_lne    <<<3072, 256, 0, stream>>>(xg_b, gt1, bt1, part1, xlnb);
    k_qkvm   <<<1024, 256, 0, stream>>>(xlnb, Wqkv, qkvb, Qb, Kf, Vf);
    k_attn   <<<1024, 256, 0, stream>>>(Qb, Kf, Vf, Ob);
    k_projm  <<<1024, 256, 0, stream>>>(Ob, Wproj, pbb, xlnb, x2b, part2);
    k_lne    <<<3072, 256, 0, stream>>>(x2b, gt2, bt2, part2, xln2b);
    k_conv2m <<<1024, 256, 0, stream>>>(xln2b, W2, c2b, params);
    k_mix    <<<1536, 256, 0, stream>>>(z, params, als, ab, out_z, out_log);
}